// Round 7
// baseline (12883.241 us; speedup 1.0000x reference)
//
#include <hip/hip_runtime.h>
#include <math.h>

// ---------------------------------------------------------------------------
// 4-layer LSTM, B=64 T=512 D=H=1024. Persistent cooperative kernel, wavefront
// schedule (layer l works on t = s - l). Round-7 changes vs round-6 (which
// spilled: WRITE_SIZE 2.24 GB of scratch):
//   - 1024 threads / 16 waves. Wave role {mat(2) x kq(4) x bhalf(2)}:
//     all 4 gates x K=256 x 32 batch rows per wave. bw[4][8]=128 regs,
//     acc[2][4]=32, a[2][8]=64 preloaded. Every A-fragment still consumed
//     by exactly ONE wave (no LDS staging, no redundant loads).
//   - __launch_bounds__(1024,1): 1 block/CU (grid-limited), 4 waves/SIMD;
//     register cap 512/wave -> no spill at ~250 demand.
//   - Proper zpl bank swizzle: bp = b ^ ((v&7)<<2) (v&7 == ln15&7 varies
//     across lanes) -> f32x4 plane writes are minimum-cycle; scalar reads
//     stride-1.
// Unchanged (r5/r6-verified): relaxed-agent store/poll barrier with one
// acquire fence, MFMA fragment conventions, fp32 gate math, h16 parity
// double-buffer, c-state in registers, 2-pass deterministic kq reduction.
// ---------------------------------------------------------------------------

#define BSZ 64
#define TSZ 512
#define DSZ 1024
#define HSZ 1024
#define LSZ 4
#define NBLK 256
#define NTHR 1024
#define NSTEP (TSZ + LSZ - 1)   // 515

typedef _Float16 half8  __attribute__((ext_vector_type(8)));
typedef _Float16 half4  __attribute__((ext_vector_type(4)));
typedef _Float16 half2v __attribute__((ext_vector_type(2)));
typedef float    f32x4  __attribute__((ext_vector_type(4)));
typedef float    f32x8  __attribute__((ext_vector_type(8)));

// workspace layout (bytes)
constexpr size_t N_X  = (size_t)BSZ * TSZ * DSZ;       // halfs
constexpr size_t N_H  = (size_t)2 * LSZ * BSZ * HSZ;   // halfs (h double buffer)
constexpr size_t OFF_X     = 0;
constexpr size_t OFF_H     = OFF_X + N_X * 2;
constexpr size_t OFF_FLAGS = OFF_H + N_H * 2;          // 256 flags, 64B apart
constexpr size_t BAR_BYTES = (size_t)NBLK * 64;

__device__ inline float sigmoidf_(float x) { return 1.0f / (1.0f + expf(-x)); }

// Single-hop all-poll grid barrier (r6-verified). Entry syncthreads drains
// this block's global stores. Post own flag (relaxed agent); threads 0..255
// poll the 256 flags in parallel; after all polls complete, ONE acquire
// fence, then syncthreads.
__device__ inline void gbar(unsigned* flags, unsigned tgt) {
  __syncthreads();
  const int t = threadIdx.x;
  if (t == 0)
    __hip_atomic_store(&flags[(size_t)blockIdx.x * 16], tgt, __ATOMIC_RELAXED,
                       __HIP_MEMORY_SCOPE_AGENT);
  if (t < NBLK) {
    while (__hip_atomic_load(&flags[(size_t)t * 16], __ATOMIC_RELAXED,
                             __HIP_MEMORY_SCOPE_AGENT) < tgt)
      __builtin_amdgcn_s_sleep(2);
  }
  __syncthreads();
  if (t == 0) __builtin_amdgcn_fence(__ATOMIC_ACQUIRE, "agent");
  __syncthreads();
}

__global__ __launch_bounds__(NTHR, 1) void lstm_persistent(
    const float* __restrict__ xin, const float* __restrict__ Wih,
    const float* __restrict__ Whh, const float* __restrict__ bih,
    const float* __restrict__ bhh, float* __restrict__ out,
    char* __restrict__ ws)
{
  _Float16* x16   = (_Float16*)(ws + OFF_X);
  _Float16* h16   = (_Float16*)(ws + OFF_H);
  unsigned* flags = (unsigned*)(ws + OFF_FLAGS);

  const int tid  = threadIdx.x;
  const int gtid = blockIdx.x * NTHR + tid;
  const int lane = tid & 63;
  const int w    = tid >> 6;        // wave 0..15
  const int mat  = w >> 3;          // 0 = input-side, 1 = recurrent
  const int kq   = (w >> 1) & 3;    // K-quarter (256 k's)
  const int bh   = w & 1;           // batch half (32 rows)
  const int ln15 = lane & 15;
  const int lq   = lane >> 4;

  const int l  = blockIdx.x >> 6;   // layer
  const int cc = blockIdx.x & 63;   // column chunk (16 H-cols)
  const int c0 = cc * 16;

  // ---- weight preload into registers (fp32 -> fp16, one time) ----
  // B-frag (r3/r5-verified): lane holds W[row = gate g, col c0+ln15] at
  // k = kq*256 + ks*32 + lq*8 + 0..7.
  const float* Wsel = mat ? Whh : Wih;
  half8 bw[4][8];
#pragma unroll
  for (int g = 0; g < 4; ++g) {
    const int grow = l * 4096 + g * 1024 + c0 + ln15;
    const float* wrow = Wsel + (size_t)grow * 1024 + kq * 256;
#pragma unroll
    for (int ks = 0; ks < 8; ++ks) {
      f32x8 f = *(const f32x8*)(wrow + ks * 32 + lq * 8);
      bw[g][ks] = __builtin_convertvector(f, half8);
    }
  }

  // ---- gate-math ownership (threads 0..511): batch row gb, cols gc/gc+1 ----
  const int gb = tid & 63;
  const int gc = (tid >> 6) * 2;    // valid for tid < 512 (gc 0..14)
  float bsg[4][2];
#pragma unroll
  for (int g = 0; g < 4; ++g) {
    const int bb = l * 4096 + g * 1024 + c0 + (tid < 512 ? gc : 0);
    bsg[g][0] = bih[bb] + bhh[bb];
    bsg[g][1] = bih[bb + 1] + bhh[bb + 1];
  }
  float cr0 = 0.f, cr1 = 0.f;       // block-private c-state (registers)

  // ---- pre-phase: cast x to fp16, zero h — relaxed agent stores ----
  {
    const f32x4* s4 = (const f32x4*)xin;
    unsigned long long* xu = (unsigned long long*)x16;
    for (int i = gtid; i < (int)(N_X / 4); i += NBLK * NTHR) {
      half4 v = __builtin_convertvector(s4[i], half4);
      __hip_atomic_store(&xu[i], __builtin_bit_cast(unsigned long long, v),
                         __ATOMIC_RELAXED, __HIP_MEMORY_SCOPE_AGENT);
    }
    unsigned long long* hz = (unsigned long long*)h16;
    for (int i = gtid; i < (int)(N_H / 4); i += NBLK * NTHR)
      __hip_atomic_store(&hz[i], 0ull, __ATOMIC_RELAXED,
                         __HIP_MEMORY_SCOPE_AGENT);
  }
  unsigned btgt = 1;
  gbar(flags, btgt++);

  // ---- LDS: partial-z planes only (exactly 64 KB) ----
  // zpl[kq][v][bp] f32; v = gate-row (g*16+col), bp = b ^ ((v&7)<<2).
  __shared__ __align__(16) float zpl[4 * 64 * 64];

  const int lm1 = (l > 0) ? (l - 1) : 0;

  for (int s = 0; s < NSTEP; ++s) {
    const int t = s - l;
    if (t >= 0 && t < TSZ) {
      const int prevslot = (s + 1) & 1;
      const _Float16* hin  = h16 + (size_t)prevslot * (LSZ * BSZ * HSZ) +
                             (size_t)lm1 * (BSZ * HSZ);
      const _Float16* hown = h16 + (size_t)prevslot * (LSZ * BSZ * HSZ) +
                             (size_t)l * (BSZ * HSZ);

      // wave-uniform activation base + per-lane element offsets
      const _Float16* bm;
      int stride;
      if (mat == 0) {
        if (l == 0) { bm = x16 + (size_t)t * DSZ; stride = TSZ * DSZ; }
        else        { bm = hin;                   stride = HSZ; }
      } else        { bm = hown;                  stride = HSZ; }
      int off[2];
#pragma unroll
      for (int mt = 0; mt < 2; ++mt)
        off[mt] = (bh * 32 + mt * 16 + ln15) * stride + kq * 256 + lq * 8;

      // ---- A preload (16 x dwordx4 in flight), then MFMA burst ----
      half8 a[2][8];
#pragma unroll
      for (int mt = 0; mt < 2; ++mt)
#pragma unroll
        for (int ks = 0; ks < 8; ++ks)
          a[mt][ks] = *(const half8*)(bm + off[mt] + ks * 32);

      f32x4 acc[2][4] = {};   // [mt][g]
#pragma unroll
      for (int ks = 0; ks < 8; ++ks)
#pragma unroll
        for (int g = 0; g < 4; ++g)
#pragma unroll
          for (int mt = 0; mt < 2; ++mt)
            acc[mt][g] = __builtin_amdgcn_mfma_f32_16x16x32_f16(
                a[mt][ks], bw[g][ks], acc[mt][g], 0, 0, 0);

      // ---- deterministic 2-pass reduction over kq via planes ----
      // C/D map (r3-verified): C row = batch = bh*32+mt*16+lq*4+r,
      // C col = gate-row v = g*16+ln15. bp = b ^ ((v&7)<<2); v&7==ln15&7
      // varies across lanes -> f32x4 writes cover all 8 bank slots.
      if (mat == 0) {
#pragma unroll
        for (int mt = 0; mt < 2; ++mt)
#pragma unroll
          for (int g = 0; g < 4; ++g) {
            const int v  = g * 16 + ln15;
            const int bp = (bh * 32 + mt * 16 + lq * 4) ^ ((ln15 & 7) << 2);
            *(f32x4*)&zpl[kq * 4096 + v * 64 + bp] = acc[mt][g];
          }
      }
      __syncthreads();
      if (mat == 1) {
#pragma unroll
        for (int mt = 0; mt < 2; ++mt)
#pragma unroll
          for (int g = 0; g < 4; ++g) {
            const int v  = g * 16 + ln15;
            const int bp = (bh * 32 + mt * 16 + lq * 4) ^ ((ln15 & 7) << 2);
            f32x4* p = (f32x4*)&zpl[kq * 4096 + v * 64 + bp];
            *p = *p + acc[mt][g];
          }
      }
      __syncthreads();

      // ---- gate math (fp32): threads 0..511, (gb, cols gc/gc+1) ----
      if (tid < 512) {
        float z[4][2];
#pragma unroll
        for (int g = 0; g < 4; ++g)
#pragma unroll
          for (int j = 0; j < 2; ++j) {
            const int v  = g * 16 + gc + j;
            const int bp = gb ^ ((v & 7) << 2);
            float sum = zpl[0 * 4096 + v * 64 + bp] +
                        zpl[1 * 4096 + v * 64 + bp] +
                        zpl[2 * 4096 + v * 64 + bp] +
                        zpl[3 * 4096 + v * 64 + bp];
            z[g][j] = sum + bsg[g][j];
          }
        float cn0 = sigmoidf_(z[1][0]) * cr0 +
                    sigmoidf_(z[0][0]) * tanhf(z[2][0]);
        float cn1 = sigmoidf_(z[1][1]) * cr1 +
                    sigmoidf_(z[0][1]) * tanhf(z[2][1]);
        float hn0 = sigmoidf_(z[3][0]) * tanhf(cn0);
        float hn1 = sigmoidf_(z[3][1]) * tanhf(cn1);
        cr0 = cn0; cr1 = cn1;
        half2v hv; hv[0] = (_Float16)hn0; hv[1] = (_Float16)hn1;
        const size_t ho = (size_t)(s & 1) * (LSZ * BSZ * HSZ) +
                          (size_t)l * (BSZ * HSZ) + (size_t)gb * HSZ + c0 + gc;
        __hip_atomic_store((unsigned*)(h16 + ho),
                           __builtin_bit_cast(unsigned, hv),
                           __ATOMIC_RELAXED, __HIP_MEMORY_SCOPE_AGENT);
        if (l == LSZ - 1 && t == TSZ - 1) {
          out[(size_t)gb * HSZ + c0 + gc]     = hn0;
          out[(size_t)gb * HSZ + c0 + gc + 1] = hn1;
        }
      }
    }
    gbar(flags, btgt++);
  }
}

extern "C" void kernel_launch(void* const* d_in, const int* in_sizes, int n_in,
                              void* d_out, int out_size, void* d_ws, size_t ws_size,
                              hipStream_t stream) {
  const float* x   = (const float*)d_in[0];
  const float* Wih = (const float*)d_in[1];
  const float* Whh = (const float*)d_in[2];
  const float* bih = (const float*)d_in[3];
  const float* bhh = (const float*)d_in[4];
  float* out = (float*)d_out;
  char*  ws  = (char*)d_ws;

  // barrier flags zeroed every call (captured in graph -> re-zeroed per replay)
  hipMemsetAsync(ws + OFF_FLAGS, 0, BAR_BYTES, stream);

  void* args[] = {(void*)&x, (void*)&Wih, (void*)&Whh, (void*)&bih,
                  (void*)&bhh, (void*)&out, (void*)&ws};
  hipLaunchCooperativeKernel((const void*)lstm_persistent, dim3(NBLK), dim3(NTHR),
                             args, 0, stream);
}

// Round 9
// 6481.865 us; speedup vs baseline: 1.9876x; 1.9876x over previous
//
#include <hip/hip_runtime.h>
#include <math.h>

// ---------------------------------------------------------------------------
// 4-layer LSTM, B=64 T=512 D=H=1024. Persistent cooperative kernel, wavefront
// schedule (layer l works on t = s - l). Round-9: back inside the PROVEN
// resource envelope (512 thr, __launch_bounds__(512,2), <=256 unified
// regs/wave, <=64KB LDS -- the r2/r8 launch failures were >256-reg configs),
// while removing r5's 4x-redundant LDS A-reads.
//   - Wave role {mat(2) x gatepair rp(2) x Khalf kh(2)}: 2 gates x K=512 of
//     one matrix. bw[2][16] half8 = 128 regs, acc[4][2] f32x4 = 32 regs.
//     A-redundancy 4x -> 2x (LDS traffic 1.25MB -> ~0.8MB per step/CU).
//   - Staging chunks interleave both K-halves: [mat][kh][64b][64h] = 32KB,
//     register-staged + ds_write_b128, XOR swizzle ((b&7)<<4) on LDS side,
//     distance-1 pipeline, double-buffered (64KB).
//   - Reduction: 2 kh-planes f32[2][64][64] (32KB, overlay buf0), swizzle
//     bp = b ^ ((v&7)<<2) (r7-proven correct + conflict-free): mat0 writes,
//     sync, mat1 accumulates, sync, gate threads sum 2 planes.
// Unchanged (r5/r6/r7-verified): relaxed-agent store/poll single-hop barrier
// + one acquire fence, MFMA fragment conventions, fp32 gate math, h16 parity
// double-buffer, c-state in registers.
// ---------------------------------------------------------------------------

#define BSZ 64
#define TSZ 512
#define DSZ 1024
#define HSZ 1024
#define LSZ 4
#define NBLK 256
#define NTHR 512
#define NSTEP (TSZ + LSZ - 1)   // 515
#define BUFB 32768               // bytes per LDS staging buffer

typedef _Float16 half8  __attribute__((ext_vector_type(8)));
typedef _Float16 half4  __attribute__((ext_vector_type(4)));
typedef _Float16 half2v __attribute__((ext_vector_type(2)));
typedef float    f32x2  __attribute__((ext_vector_type(2)));
typedef float    f32x4  __attribute__((ext_vector_type(4)));
typedef float    f32x8  __attribute__((ext_vector_type(8)));

// workspace layout (bytes)
constexpr size_t N_X  = (size_t)BSZ * TSZ * DSZ;       // halfs
constexpr size_t N_H  = (size_t)2 * LSZ * BSZ * HSZ;   // halfs (h double buffer)
constexpr size_t OFF_X     = 0;
constexpr size_t OFF_H     = OFF_X + N_X * 2;
constexpr size_t OFF_FLAGS = OFF_H + N_H * 2;          // 256 flags, 64B apart
constexpr size_t BAR_BYTES = (size_t)NBLK * 64;

__device__ inline float sigmoidf_(float x) { return 1.0f / (1.0f + expf(-x)); }

// Single-hop all-poll grid barrier (r6/r7-verified). Entry syncthreads drains
// this block's global stores. Post own flag (relaxed agent); threads 0..255
// poll the 256 flags in parallel; after all polls complete, ONE acquire
// fence, then syncthreads.
__device__ inline void gbar(unsigned* flags, unsigned tgt) {
  __syncthreads();
  const int t = threadIdx.x;
  if (t == 0)
    __hip_atomic_store(&flags[(size_t)blockIdx.x * 16], tgt, __ATOMIC_RELAXED,
                       __HIP_MEMORY_SCOPE_AGENT);
  if (t < NBLK) {
    while (__hip_atomic_load(&flags[(size_t)t * 16], __ATOMIC_RELAXED,
                             __HIP_MEMORY_SCOPE_AGENT) < tgt)
      __builtin_amdgcn_s_sleep(2);
  }
  __syncthreads();
  if (t == 0) __builtin_amdgcn_fence(__ATOMIC_ACQUIRE, "agent");
  __syncthreads();
}

__global__ __launch_bounds__(NTHR, 2) void lstm_persistent(
    const float* __restrict__ xin, const float* __restrict__ Wih,
    const float* __restrict__ Whh, const float* __restrict__ bih,
    const float* __restrict__ bhh, float* __restrict__ out,
    char* __restrict__ ws)
{
  _Float16* x16   = (_Float16*)(ws + OFF_X);
  _Float16* h16   = (_Float16*)(ws + OFF_H);
  unsigned* flags = (unsigned*)(ws + OFF_FLAGS);

  const int tid  = threadIdx.x;
  const int gtid = blockIdx.x * NTHR + tid;
  const int lane = tid & 63;
  const int w    = tid >> 6;        // wave 0..7
  const int mat  = w >> 2;          // 0 = input-side, 1 = recurrent
  const int rp   = (w >> 1) & 1;    // gate pair (gates 2rp, 2rp+1)
  const int kh   = w & 1;           // K-half (512 k's)
  const int ln15 = lane & 15;
  const int lq   = lane >> 4;

  const int l  = blockIdx.x >> 6;   // layer
  const int cc = blockIdx.x & 63;   // column chunk (16 H-cols)
  const int c0 = cc * 16;

  // ---- weight preload into registers (fp32 -> fp16, one time) ----
  // B-frag (r3/r5-verified): lane holds W[row = gate 2rp+gl, col c0+ln15]
  // at k = kh*512 + ks*32 + lq*8 + 0..7. bw[gl][ks] = 128 regs.
  const float* Wsel = mat ? Whh : Wih;
  half8 bw[2][16];
#pragma unroll
  for (int gl = 0; gl < 2; ++gl) {
    const float* wrow =
        Wsel + (size_t)(l * 4096 + (rp * 2 + gl) * 1024 + c0 + ln15) * 1024 +
        kh * 512;
#pragma unroll
    for (int ks = 0; ks < 16; ++ks) {
      f32x8 f = *(const f32x8*)(wrow + ks * 32 + lq * 8);
      bw[gl][ks] = __builtin_convertvector(f, half8);
    }
  }

  // ---- gate-math ownership: batch row gb, column pair gc/gc+1 ----
  const int gb = tid & 63;
  const int gc = (tid >> 6) * 2;    // even col 0..14
  float bsg[4][2];
#pragma unroll
  for (int g = 0; g < 4; ++g) {
    const int bb = l * 4096 + g * 1024 + c0 + gc;
    bsg[g][0] = bih[bb] + bhh[bb];
    bsg[g][1] = bih[bb + 1] + bhh[bb + 1];
  }
  float cr0 = 0.f, cr1 = 0.f;       // block-private c-state (registers)

  // ---- precomputed staging decomposition (step-invariant) ----
  // chunk layout: [mat][kh][64 b][64 halfs], 32KB; swizzle ((b&7)<<4).
  int st_mat[4], st_b[4], st_so[4], st_ds[4];
#pragma unroll
  for (int it = 0; it < 4; ++it) {
    const int idx = it * NTHR + tid;        // 0..2047 16B-slots
    st_mat[it] = idx >> 10;
    const int khs = (idx >> 9) & 1;
    const int b   = (idx >> 3) & 63;
    const int sl  = idx & 7;
    st_b[it]  = b;
    st_so[it] = khs * 1024 + sl * 16;       // byte offset within source row
    st_ds[it] = st_mat[it] * 16384 + khs * 8192 + b * 128 +
                ((sl * 16) ^ ((b & 7) << 4));
  }

  // ---- pre-phase: cast x to fp16, zero h — relaxed agent stores ----
  {
    const f32x4* s4 = (const f32x4*)xin;
    unsigned long long* xu = (unsigned long long*)x16;
    for (int i = gtid; i < (int)(N_X / 4); i += NBLK * NTHR) {
      half4 v = __builtin_convertvector(s4[i], half4);
      __hip_atomic_store(&xu[i], __builtin_bit_cast(unsigned long long, v),
                         __ATOMIC_RELAXED, __HIP_MEMORY_SCOPE_AGENT);
    }
    unsigned long long* hz = (unsigned long long*)h16;
    for (int i = gtid; i < (int)(N_H / 4); i += NBLK * NTHR)
      __hip_atomic_store(&hz[i], 0ull, __ATOMIC_RELAXED,
                         __HIP_MEMORY_SCOPE_AGENT);
  }
  unsigned btgt = 1;
  gbar(flags, btgt++);

  // ---- LDS: 2 staging buffers (32KB each); planes overlay buf0 ----
  __shared__ __align__(16) char smem[2 * BUFB];
  float* pl = (float*)smem;        // f32[2][64][64] after final compute sync

  const int lm1 = (l > 0) ? (l - 1) : 0;

  for (int s = 0; s < NSTEP; ++s) {
    const int t = s - l;
    if (t >= 0 && t < TSZ) {
      const int prevslot = (s + 1) & 1;
      const _Float16* hin  = h16 + (size_t)prevslot * (LSZ * BSZ * HSZ) +
                             (size_t)lm1 * (BSZ * HSZ);
      const _Float16* hown = h16 + (size_t)prevslot * (LSZ * BSZ * HSZ) +
                             (size_t)l * (BSZ * HSZ);
      const _Float16* base0 = (l == 0) ? x16 + (size_t)t * DSZ : hin;
      const size_t    str0  = (l == 0) ? (size_t)TSZ * DSZ : (size_t)HSZ;

      // stage one chunk: K[kc*64..+64) of both K-halves, both mats
      auto stage_load = [&](int kc, half8 (&v)[4]) {
#pragma unroll
        for (int it = 0; it < 4; ++it) {
          const _Float16* rb = st_mat[it] ? hown + (size_t)st_b[it] * HSZ
                                          : base0 + (size_t)st_b[it] * str0;
          v[it] = *(const half8*)((const char*)rb + kc * 128 + st_so[it]);
        }
      };
      auto stage_write = [&](half8 (&v)[4], int bsel) {
#pragma unroll
        for (int it = 0; it < 4; ++it)
          *(half8*)(smem + bsel * BUFB + st_ds[it]) = v[it];
      };

      f32x4 acc[4][2] = {};   // [mt][gl]
      half8 vs[4];

      stage_load(0, vs);
      stage_write(vs, 0);
      __syncthreads();

      const int rdoff = mat * 16384 + kh * 8192;
#pragma unroll
      for (int kc = 0; kc < 8; ++kc) {
        if (kc < 7) stage_load(kc + 1, vs);
        const char* rdb = smem + (kc & 1) * BUFB + rdoff;
#pragma unroll
        for (int ksl = 0; ksl < 2; ++ksl) {
          half8 a[4];
#pragma unroll
          for (int mt = 0; mt < 4; ++mt) {
            const int row = mt * 16 + ln15;
            a[mt] = *(const half8*)(rdb + row * 128 +
                                    ((ksl * 64 + lq * 16) ^ ((row & 7) << 4)));
          }
#pragma unroll
          for (int gl = 0; gl < 2; ++gl)
#pragma unroll
            for (int mt = 0; mt < 4; ++mt)
              acc[mt][gl] = __builtin_amdgcn_mfma_f32_16x16x32_f16(
                  a[mt], bw[gl][kc * 2 + ksl], acc[mt][gl], 0, 0, 0);
        }
        if (kc < 7) stage_write(vs, (kc + 1) & 1);
        __syncthreads();
      }

      // ---- kh-plane reduction (mat0 writes, mat1 accumulates) ----
      // C/D map (r3-verified): C row = batch = mt*16+lq*4+r,
      // C col = gate-row v = (2rp+gl)*16+ln15. bp = b ^ ((v&7)<<2).
      if (mat == 0) {
#pragma unroll
        for (int mt = 0; mt < 4; ++mt)
#pragma unroll
          for (int gl = 0; gl < 2; ++gl) {
            const int v  = (rp * 2 + gl) * 16 + ln15;
            const int bp = (mt * 16 + lq * 4) ^ ((ln15 & 7) << 2);
            *(f32x4*)&pl[kh * 4096 + v * 64 + bp] = acc[mt][gl];
          }
      }
      __syncthreads();
      if (mat == 1) {
#pragma unroll
        for (int mt = 0; mt < 4; ++mt)
#pragma unroll
          for (int gl = 0; gl < 2; ++gl) {
            const int v  = (rp * 2 + gl) * 16 + ln15;
            const int bp = (mt * 16 + lq * 4) ^ ((ln15 & 7) << 2);
            f32x4* p = (f32x4*)&pl[kh * 4096 + v * 64 + bp];
            *p = *p + acc[mt][gl];
          }
      }
      __syncthreads();

      // ---- gate math (fp32): thread owns (gb, cols gc/gc+1) ----
      {
        float z[4][2];
#pragma unroll
        for (int g = 0; g < 4; ++g)
#pragma unroll
          for (int j = 0; j < 2; ++j) {
            const int v  = g * 16 + gc + j;
            const int bp = gb ^ ((v & 7) << 2);
            z[g][j] = pl[0 * 4096 + v * 64 + bp] +
                      pl[1 * 4096 + v * 64 + bp] + bsg[g][j];
          }
        float cn0 = sigmoidf_(z[1][0]) * cr0 +
                    sigmoidf_(z[0][0]) * tanhf(z[2][0]);
        float cn1 = sigmoidf_(z[1][1]) * cr1 +
                    sigmoidf_(z[0][1]) * tanhf(z[2][1]);
        float hn0 = sigmoidf_(z[3][0]) * tanhf(cn0);
        float hn1 = sigmoidf_(z[3][1]) * tanhf(cn1);
        cr0 = cn0; cr1 = cn1;
        half2v hv; hv[0] = (_Float16)hn0; hv[1] = (_Float16)hn1;
        const size_t ho = (size_t)(s & 1) * (LSZ * BSZ * HSZ) +
                          (size_t)l * (BSZ * HSZ) + (size_t)gb * HSZ + c0 + gc;
        __hip_atomic_store((unsigned*)(h16 + ho),
                           __builtin_bit_cast(unsigned, hv),
                           __ATOMIC_RELAXED, __HIP_MEMORY_SCOPE_AGENT);
        if (l == LSZ - 1 && t == TSZ - 1) {
          out[(size_t)gb * HSZ + c0 + gc]     = hn0;
          out[(size_t)gb * HSZ + c0 + gc + 1] = hn1;
        }
      }
    }
    gbar(flags, btgt++);
  }
}

extern "C" void kernel_launch(void* const* d_in, const int* in_sizes, int n_in,
                              void* d_out, int out_size, void* d_ws, size_t ws_size,
                              hipStream_t stream) {
  const float* x   = (const float*)d_in[0];
  const float* Wih = (const float*)d_in[1];
  const float* Whh = (const float*)d_in[2];
  const float* bih = (const float*)d_in[3];
  const float* bhh = (const float*)d_in[4];
  float* out = (float*)d_out;
  char*  ws  = (char*)d_ws;

  // barrier flags zeroed every call (captured in graph -> re-zeroed per replay)
  hipMemsetAsync(ws + OFF_FLAGS, 0, BAR_BYTES, stream);

  void* args[] = {(void*)&x, (void*)&Wih, (void*)&Whh, (void*)&bih,
                  (void*)&bhh, (void*)&out, (void*)&ws};
  hipLaunchCooperativeKernel((const void*)lstm_persistent, dim3(NBLK), dim3(NTHR),
                             args, 0, stream);
}